// Round 7
// baseline (239.474 us; speedup 1.0000x reference)
//
#include <hip/hip_runtime.h>
#include <math.h>

// Problem constants (reference: B=64, TK=512, NK=256, H=512, fp32 in/out)
constexpr int kB = 64;
constexpr int kTK = 512;
constexpr int kNK = 256;
constexpr int kH = 512;

typedef float f32x4 __attribute__((ext_vector_type(4)));
typedef __bf16 bf16x8 __attribute__((ext_vector_type(8)));

__device__ __forceinline__ unsigned short f32_to_bf16(float f) {
  return (unsigned short)((__float_as_uint(f) + 0x8000u) >> 16);
}

__device__ __forceinline__ float tanh_fast(float x) {
  float e = __builtin_amdgcn_exp2f(x * 2.8853900817779268f);  // e^{2x}
  return 1.0f - 2.0f * __builtin_amdgcn_rcpf(e + 1.0f);
}

// CK-style: drain LDS only, leave global loads in flight across the barrier.
__device__ __forceinline__ void lds_barrier() {
  __builtin_amdgcn_s_waitcnt(0xC07F);
  __builtin_amdgcn_s_barrier();
}

// Async global->LDS, 16B per lane. LDS dest = wave-uniform base + lane*16.
__device__ __forceinline__ void gload_lds16(const void* g, void* l) {
  __builtin_amdgcn_global_load_lds(
      (__attribute__((address_space(1))) void*)(g),
      (__attribute__((address_space(3))) void*)(l), 16, 0, 0);
}

// ---------------------------------------------------------- prep kernel
// blocks [0,512): W transpose->bf16 [n][k]; blocks [512,1024): dec partials.
__global__ __launch_bounds__(256) void prep_kernel(
    const float* __restrict__ Wtok, const float* __restrict__ Wnode,
    unsigned short* __restrict__ WtokT, unsigned short* __restrict__ WnodeT,
    const float* __restrict__ s_t_hat, const float* __restrict__ W_dec,
    float* __restrict__ dec_part) {
  __shared__ float sm[32 * 33];
  const int tid = threadIdx.x;
  if (blockIdx.x < 512) {
    const int idx = blockIdx.x;
    const int z = idx >> 8, rem = idx & 255;
    const int bx = rem & 15, by = rem >> 4;
    const float* W = z ? Wnode : Wtok;
    unsigned short* T = z ? WnodeT : WtokT;
    const int tx = tid & 31, ty = tid >> 5;
#pragma unroll
    for (int i = 0; i < 4; ++i)
      sm[(ty + 8 * i) * 33 + tx] =
          W[(size_t)(by * 32 + ty + 8 * i) * kH + bx * 32 + tx];
    __syncthreads();
#pragma unroll
    for (int i = 0; i < 4; ++i)
      T[(size_t)(bx * 32 + ty + 8 * i) * kH + by * 32 + tx] =
          f32_to_bf16(sm[tx * 33 + ty + 8 * i]);
  } else {
    const int r = blockIdx.x - 512;
    const int b = r >> 3, s = r & 7;
    if (tid < 128) sm[tid] = s_t_hat[(size_t)b * 1024 + s * 128 + tid];
    __syncthreads();
    float a0 = 0.f, a1 = 0.f;
    const float* w = W_dec + (size_t)(s * 128) * kH;
#pragma unroll 8
    for (int k = 0; k < 128; ++k) {
      a0 = fmaf(sm[k], w[(size_t)k * kH + tid], a0);
      a1 = fmaf(sm[k], w[(size_t)k * kH + tid + 256], a1);
    }
    dec_part[(size_t)(b * 8 + s) * kH + tid] = a0;
    dec_part[(size_t)(b * 8 + s) * kH + tid + 256] = a1;
  }
}

// ---------------------------------------------------------- fused scores
// SPLIT-N geometry (round 7): 256 threads = 4 waves; block tile 64 rows x
// 256 cols (colhalf of 512); grid 1536 = 6 blocks/CU in two full residency
// rounds. Per-wave structure identical to round 6 (BK=64, gload_lds raw f32,
// cooperative f32->bf16 cvt into XOR-swizzled hbuf, B 2-phase register ring,
// setprio around MFMA). Why: rounds 0-6 all sat at 75-100us with every pipe
// <16% -- latency-bound with ~1.4 resident 8-wave blocks = ONE barrier
// domain per CU. With 4-wave blocks, each resident block contributes exactly
// one wave per SIMD, so the 3 waves/SIMD belong to 3 INDEPENDENT barrier
// domains: one block's vmcnt(0)/barrier stall is covered by the other two.
// LDS 49KB x3 = 147KB resident; regs ~136 combined -> 3 waves/SIMD (cap 170
// via (256,3); the (512,4) cap=128 forced-spill of rounds 4-6 is gone).
// The col-split tanh.v reduction writes PARTIAL scores per colhalf; the
// softmax kernel sums the two halves (deterministic, no atomics).
__global__ __launch_bounds__(256, 3) void scores_fused_kernel(
    const float* __restrict__ enc_tok, const float* __restrict__ enc_node,
    const unsigned short* __restrict__ WtokT,
    const unsigned short* __restrict__ WnodeT,
    const float* __restrict__ dec_part, const float* __restrict__ b_dec,
    const float* __restrict__ flow, const float* __restrict__ W_c,
    const float* __restrict__ v_tok, const float* __restrict__ v_node,
    float* __restrict__ scores_tok, float* __restrict__ scores_node) {
  const int tid = threadIdx.x;
  const int wave = tid >> 6, lane = tid & 63;
  const int quad = lane >> 4, l15 = lane & 15;
  // blocks [0,1024): token (512 row-tiles x 2 colhalves)
  // blocks [1024,1536): node (256 row-tiles x 2 colhalves)
  const bool is_node = blockIdx.x >= 1024;
  int bx = is_node ? (int)blockIdx.x - 1024 : (int)blockIdx.x;
  const int colhalf = bx & 1;
  bx >>= 1;
  const float* A = is_node ? enc_node : enc_tok;
  const unsigned short* WT = is_node ? WnodeT : WtokT;
  const float* v = is_node ? v_node : v_tok;
  const int ROWS = is_node ? kNK : kTK;
  const int b = is_node ? (bx >> 2) : (bx >> 3);
  const int row0 = (is_node ? (bx & 3) : (bx & 7)) * 64;
  float* scores = (is_node ? scores_node : scores_tok) +
                  (size_t)colhalf * (kB * ROWS);

  __shared__ __align__(16) float fbuf[2][4096];           // 16 KB x2, f32 [64][64] linear
  __shared__ __align__(16) unsigned short hbuf[2][4096];  // 8 KB x2, bf16 [64][64] swizzled
  __shared__ float red[4][64];

  const f32x4 fzero = {0.f, 0.f, 0.f, 0.f};
  f32x4 acc[4][4];
#pragma unroll
  for (int i = 0; i < 4; ++i)
#pragma unroll
    for (int j = 0; j < 4; ++j) acc[i][j] = fzero;

  // --- A staging (raw f32, linear) ----------------------------------
  // wave w stages rows [16w, 16w+16): 4 gload_lds16 of 4 rows (1 KB) each.
  const float* asrcw =
      A + (size_t)(b * ROWS + row0 + wave * 16 + (lane >> 4)) * kH + (lane & 15) * 4;
  auto stage = [&](int kc, int buf) {
#pragma unroll
    for (int j = 0; j < 4; ++j)
      gload_lds16(asrcw + (size_t)(4 * j) * kH + kc * 64,
                  &fbuf[buf][(wave * 16 + 4 * j) * 64]);
  };

  // --- cooperative chunk conversion fbuf -> hbuf (swizzled) ---------
  // 256 threads x 4 f32x4 each = 4096 elements. hbuf byte addr for element
  // (row,k): row*128 + ((k>>3)^(row&7))*16 + (k&7)*2 (round-6 verified).
  auto cvt = [&](int buf) {
#pragma unroll
    for (int j = 0; j < 4; ++j) {
      const int e0 = j * 1024 + tid * 4;
      const int row = e0 >> 6, k = e0 & 63;
      const f32x4 x = *(const f32x4*)&fbuf[buf][e0];
      ushort4 h;
      h.x = f32_to_bf16(x[0]); h.y = f32_to_bf16(x[1]);
      h.z = f32_to_bf16(x[2]); h.w = f32_to_bf16(x[3]);
      const int s16 = (k >> 3) ^ (row & 7);
      *(ushort4*)((char*)&hbuf[buf][0] + row * 128 + s16 * 16 + (k & 7) * 2) = h;
    }
  };

  // --- frag read: pure bf16 ds_read_b128 ----------------------------
  auto readfrag = [&](int buf, int ks, int mi) {
    const int row = mi * 16 + l15;
    const int s16 = (ks * 4 + quad) ^ (row & 7);
    return *(const bf16x8*)((const char*)&hbuf[buf][0] + row * 128 + s16 * 16);
  };

  // B: wave owns cols [colhalf*256 + 64w, +64): 4 n-tiles, 2 phases.
  const int n0 = colhalf * 256 + wave * 64;
  const unsigned short* bbase = WT + (size_t)(n0 + l15) * kH + quad * 8;
  bf16x8 bbuf[2][2];  // set0 = n-tiles {0,1}, set1 = n-tiles {2,3}
  auto loadB = [&](int sb, int g, int half) {
    bbuf[sb][0] = *(const bf16x8*)(bbase + (size_t)(16 * (2 * half + 0)) * kH + g * 32);
    bbuf[sb][1] = *(const bf16x8*)(bbase + (size_t)(16 * (2 * half + 1)) * kH + g * 32);
  };

  stage(0, 0);
  loadB(0, 0, 0);
  loadB(1, 0, 1);

#pragma unroll
  for (int kc = 0; kc < 8; ++kc) {
    __builtin_amdgcn_s_waitcnt(0x0F70);   // vmcnt(0): fbuf[kc&1] landed
    __builtin_amdgcn_sched_barrier(0);    // rule #18: pin the wait
    cvt(kc & 1);
    if (kc < 7) stage(kc + 1, (kc + 1) & 1);
    lds_barrier();                        // hbuf[kc&1] visible; DMA flies across
#pragma unroll
    for (int ks = 0; ks < 2; ++ks) {
      const int g = kc * 2 + ks;
      bf16x8 afr[4];
#pragma unroll
      for (int mi = 0; mi < 4; ++mi) afr[mi] = readfrag(kc & 1, ks, mi);
      // phase 0: n-tiles 0,1 from set0; refill set1 with (g, phase1)
      if (g > 0) loadB(1, g, 1);
      __builtin_amdgcn_s_setprio(1);
#pragma unroll
      for (int mi = 0; mi < 4; ++mi)
#pragma unroll
        for (int ni = 0; ni < 2; ++ni)
          acc[mi][ni] = __builtin_amdgcn_mfma_f32_16x16x32_bf16(
              afr[mi], bbuf[0][ni], acc[mi][ni], 0, 0, 0);
      __builtin_amdgcn_s_setprio(0);
      // phase 1: n-tiles 2,3 from set1; refill set0 with (g+1, phase0)
      if (g < 15) loadB(0, g + 1, 0);
      __builtin_amdgcn_s_setprio(1);
#pragma unroll
      for (int mi = 0; mi < 4; ++mi)
#pragma unroll
        for (int ni = 0; ni < 2; ++ni)
          acc[mi][ni + 2] = __builtin_amdgcn_mfma_f32_16x16x32_bf16(
              afr[mi], bbuf[1][ni], acc[mi][ni + 2], 0, 0, 0);
      __builtin_amdgcn_s_setprio(0);
    }
  }

  // epilogue; C/D: col = n0+16ni+l15, row = 16mi+quad*4+reg.
  // PARTIAL over this block's 256 cols; softmax sums the two halves.
  float dec2[4], vv2[4], wc2[4];
#pragma unroll
  for (int ni = 0; ni < 4; ++ni) {
    const int col = n0 + 16 * ni + l15;
    float d = b_dec[col];
#pragma unroll
    for (int p = 0; p < 8; ++p) d += dec_part[(size_t)(b * 8 + p) * kH + col];
    dec2[ni] = d;
    vv2[ni] = v[col];
    wc2[ni] = is_node ? W_c[col] : 0.f;
  }
#pragma unroll
  for (int mi = 0; mi < 4; ++mi) {
#pragma unroll
    for (int reg = 0; reg < 4; ++reg) {
      const int row = 16 * mi + quad * 4 + reg;
      const float fl = is_node ? flow[b * kNK + row0 + row] : 0.f;
      float p = 0.f;
#pragma unroll
      for (int ni = 0; ni < 4; ++ni)
        p += tanh_fast(fmaf(fl, wc2[ni], acc[mi][ni][reg] + dec2[ni])) * vv2[ni];
#pragma unroll
      for (int off = 1; off < 16; off <<= 1) p += __shfl_xor(p, off, 64);
      if (l15 == 0) red[wave][row] = p;
    }
  }
  __syncthreads();
  if (tid < 64) {
    float s = 0.f;
#pragma unroll
    for (int w = 0; w < 4; ++w) s += red[w][tid];
    scores[b * ROWS + row0 + tid] = s;
  }
}

// ---------------------------------------------------------- softmax/mix (+zero flow)
__device__ __forceinline__ float block_sum_512(float v, float* rbuf) {
#pragma unroll
  for (int off = 32; off >= 1; off >>= 1) v += __shfl_xor(v, off, 64);
  if ((threadIdx.x & 63) == 0) rbuf[threadIdx.x >> 6] = v;
  __syncthreads();
  float s = rbuf[0];
#pragma unroll
  for (int w = 1; w < 8; ++w) s += rbuf[w];
  __syncthreads();
  return s;
}

__global__ __launch_bounds__(512) void softmax_mix_kernel(
    const float* __restrict__ scores_node, const float* __restrict__ scores_tok,
    const int* __restrict__ node_to_token,
    const float* __restrict__ mask_tok, const float* __restrict__ mask_node,
    float* __restrict__ out_final, float* __restrict__ out_attn_node,
    float* __restrict__ out_flow) {
  const int b = blockIdx.x, tid = threadIdx.x;
  __shared__ float an_sh[kNK];
  __shared__ float rbuf[8];

  if (tid < kNK) out_flow[b * kNK + tid] = 0.f;  // init for flow2 atomics

  float en = 0.f;
  if (tid < kNK) {
    const float s2 = scores_node[b * kNK + tid] +
                     scores_node[kB * kNK + b * kNK + tid];  // colhalf partials
    en = expf(s2) * mask_node[b * kNK + tid];
  }
  float sn = block_sum_512(en, rbuf);
  float an = en / sn;
  if (tid < kNK) {
    an_sh[tid] = an;
    out_attn_node[b * kNK + tid] = an;
  }
  __syncthreads();

  const float mt = mask_tok[b * kTK + tid];
  const int idx = node_to_token[b * kTK + tid];
  float eg = expf(an_sh[idx]) * mt;
  float sg = block_sum_512(eg, rbuf);
  float an2t = eg / sg;

  const float st2 = scores_tok[b * kTK + tid] +
                    scores_tok[kB * kTK + b * kTK + tid];    // colhalf partials
  float et = expf(st2) * mt;
  float st = block_sum_512(et, rbuf);
  float at = et / st;

  out_final[b * kTK + tid] = 0.5f * (at + an2t);
}

// ---------------------------------------------------------- ct_partial + flow1
// blocks [0,512): ct partial (b, 64-row slice s of 8): 4 sub-accumulators of
//   16 rows each, reduced in LDS -> ctp[b*8+s][512].
// blocks [512,768): one_hop partials (b, sl of 64 n-rows), float4 over m,
//   in-block reduce over nsub -> fp1[b][4][256].
__global__ __launch_bounds__(512) void ct_flow1_kernel(
    const float* __restrict__ final_attn, const float* __restrict__ enc_tok,
    const float* __restrict__ attn_node, const float* __restrict__ graph,
    float* __restrict__ ctp, float* __restrict__ fp1) {
  const int tid = threadIdx.x;
  if (blockIdx.x < 512) {
    const int b = blockIdx.x >> 3, s = blockIdx.x & 7;
    __shared__ float fa[64];
    __shared__ float part[4][512];
    if (tid < 64) fa[tid] = final_attn[b * kTK + s * 64 + tid];
    __syncthreads();
    const int h4 = (tid & 127) * 4, tsub = tid >> 7;   // 4 tsubs x 16 rows
    float4 acc = {0.f, 0.f, 0.f, 0.f};
    const float* base =
        enc_tok + ((size_t)(b * kTK + s * 64 + tsub * 16)) * kH + h4;
#pragma unroll
    for (int t = 0; t < 16; ++t) {
      float4 e = *(const float4*)(base + (size_t)t * kH);
      const float w = fa[tsub * 16 + t];
      acc.x = fmaf(w, e.x, acc.x); acc.y = fmaf(w, e.y, acc.y);
      acc.z = fmaf(w, e.z, acc.z); acc.w = fmaf(w, e.w, acc.w);
    }
    *(float4*)&part[tsub][h4] = acc;
    __syncthreads();
    if (tid < 128) {
      float4 s0 = {0.f, 0.f, 0.f, 0.f};
#pragma unroll
      for (int p = 0; p < 4; ++p) {
        float4 pp = *(const float4*)&part[p][tid * 4];
        s0.x += pp.x; s0.y += pp.y; s0.z += pp.z; s0.w += pp.w;
      }
      *(float4*)&ctp[((size_t)(b * 8 + s)) * kH + tid * 4] = s0;
    }
  } else {
    const int rr = blockIdx.x - 512;
    const int b = rr >> 2, sl = rr & 3;
    __shared__ float z[64];
    __shared__ float part[8][256];
    if (tid < 64) z[tid] = attn_node[b * kNK + sl * 64 + tid];
    __syncthreads();
    const int m4 = (tid & 63) * 4, nsub = tid >> 6;
    float4 acc = {0.f, 0.f, 0.f, 0.f};
    const float* g =
        graph + ((size_t)(b * kNK + sl * 64 + nsub * 8)) * kNK + m4;
#pragma unroll
    for (int n = 0; n < 8; ++n) {
      float4 gg = *(const float4*)(g + (size_t)n * kNK);
      const float w = z[nsub * 8 + n];
      acc.x = fmaf(w, gg.x, acc.x); acc.y = fmaf(w, gg.y, acc.y);
      acc.z = fmaf(w, gg.z, acc.z); acc.w = fmaf(w, gg.w, acc.w);
    }
    *(float4*)&part[nsub][m4] = acc;
    __syncthreads();
    if (tid < 64) {
      float4 s0 = {0.f, 0.f, 0.f, 0.f};
#pragma unroll
      for (int p = 0; p < 8; ++p) {
        float4 pp = *(const float4*)&part[p][tid * 4];
        s0.x += pp.x; s0.y += pp.y; s0.z += pp.z; s0.w += pp.w;
      }
      *(float4*)&fp1[((size_t)(b * 4 + sl)) * kNK + tid * 4] = s0;
    }
  }
}

// ---------------------------------------------------------- ct_reduce + flow 2-hop
__global__ __launch_bounds__(512) void ct_flow2_kernel(
    const float* __restrict__ ctp, const float* __restrict__ fp1,
    const float* __restrict__ attn_node, const float* __restrict__ graph,
    float* __restrict__ out_ct, float* __restrict__ out_flow) {
  const int tid = threadIdx.x;
  if (blockIdx.x < 64) {
    const int b = blockIdx.x;
    __shared__ float acc_sh[4][512];
    const int h4 = (tid & 127) * 4, part = tid >> 7;
    float4 a = {0.f, 0.f, 0.f, 0.f};
#pragma unroll
    for (int j = 0; j < 2; ++j) {
      float4 c = *(const float4*)&ctp[((size_t)(b * 8 + part * 2 + j)) * kH + h4];
      a.x += c.x; a.y += c.y; a.z += c.z; a.w += c.w;
    }
    *(float4*)&acc_sh[part][h4] = a;
    __syncthreads();
    if (tid < 128) {
      float4 s = {0.f, 0.f, 0.f, 0.f};
#pragma unroll
      for (int p = 0; p < 4; ++p) {
        float4 pp = *(const float4*)&acc_sh[p][tid * 4];
        s.x += pp.x; s.y += pp.y; s.z += pp.z; s.w += pp.w;
      }
      *(float4*)&out_ct[b * kH + tid * 4] = s;
    }
  } else {
    const int rr = blockIdx.x - 64;
    const int b = rr >> 2, sl = rr & 3;
    __shared__ float one_sh[64];
    __shared__ float part2[8][256];
    if (tid < 64) {
      const int n = sl * 64 + tid;
      float one = 0.f;
#pragma unroll
      for (int p = 0; p < 4; ++p) one += fp1[((size_t)(b * 4 + p)) * kNK + n];
      one_sh[tid] = one;
      atomicAdd(&out_flow[b * kNK + n],
                (attn_node[b * kNK + n] + one) * 0.33333f);
    }
    __syncthreads();
    const int m4 = (tid & 63) * 4, nsub = tid >> 6;
    float4 acc = {0.f, 0.f, 0.f, 0.f};
    const float* g =
        graph + ((size_t)(b * kNK + sl * 64 + nsub * 8)) * kNK + m4;
#pragma unroll
    for (int n = 0; n < 8; ++n) {
      float4 gg = *(const float4*)(g + (size_t)n * kNK);
      const float w = one_sh[sl * 0 + nsub * 8 + n];
      acc.x = fmaf(w, gg.x, acc.x); acc.y = fmaf(w, gg.y, acc.y);
      acc.z = fmaf(w, gg.z, acc.z); acc.w = fmaf(w, gg.w, acc.w);
    }
    *(float4*)&part2[nsub][m4] = acc;
    __syncthreads();
    if (tid < 64) {
      float4 s = {0.f, 0.f, 0.f, 0.f};
#pragma unroll
      for (int p = 0; p < 8; ++p) {
        float4 pp = *(const float4*)&part2[p][tid * 4];
        s.x += pp.x; s.y += pp.y; s.z += pp.z; s.w += pp.w;
      }
      float* dst = &out_flow[b * kNK + tid * 4];
      atomicAdd(dst + 0, s.x * 0.33333f);
      atomicAdd(dst + 1, s.y * 0.33333f);
      atomicAdd(dst + 2, s.z * 0.33333f);
      atomicAdd(dst + 3, s.w * 0.33333f);
    }
  }
}

// ---------------------------------------------------------------- launch
extern "C" void kernel_launch(void* const* d_in, const int* in_sizes, int n_in,
                              void* d_out, int out_size, void* d_ws, size_t ws_size,
                              hipStream_t stream) {
  (void)in_sizes; (void)n_in; (void)out_size; (void)ws_size;
  const float* s_t_hat  = (const float*)d_in[0];
  const float* enc_tok  = (const float*)d_in[1];
  const float* enc_node = (const float*)d_in[2];
  const int*   n2t      = (const int*)d_in[3];
  const float* mask_tok = (const float*)d_in[4];
  const float* mask_nd  = (const float*)d_in[5];
  const float* graph    = (const float*)d_in[6];
  const float* flow     = (const float*)d_in[7];
  const float* W_c      = (const float*)d_in[8];
  const float* W_tok    = (const float*)d_in[9];
  const float* W_node   = (const float*)d_in[10];
  const float* W_dec    = (const float*)d_in[11];
  const float* b_dec    = (const float*)d_in[12];
  const float* v_tok    = (const float*)d_in[13];
  const float* v_node   = (const float*)d_in[14];

  float* out = (float*)d_out;   // c_t | final_attn | attn_dist_node | flow_out
  float* out_ct        = out;
  float* out_final     = out + kB * kH;
  float* out_attn_node = out + 2 * kB * kH;
  float* out_flow      = out_attn_node + kB * kNK;

  // workspace (float offsets), ~2.23 MB:
  float* ws = (float*)d_ws;
  float* scores_tok  = ws;                    // 2 x 32768 (colhalf partials)
  float* scores_node = ws + 65536;            // 2 x 16384 (colhalf partials)
  float* dec_part    = ws + 98304;            // 262144 (consumed by scores)
  float* ctp         = dec_part;              // alias: 64*8*512 = 262144
  float* fp1         = ws + 360448;           // 64*4*256 = 65536
  unsigned short* WtokT  = (unsigned short*)(ws + 425984);  // 65536 f
  unsigned short* WnodeT = WtokT + kH * kH;                 // 65536 f

  prep_kernel<<<1024, 256, 0, stream>>>(W_tok, W_node, WtokT, WnodeT,
                                        s_t_hat, W_dec, dec_part);
  scores_fused_kernel<<<1536, 256, 0, stream>>>(
      enc_tok, enc_node, WtokT, WnodeT, dec_part, b_dec, flow, W_c,
      v_tok, v_node, scores_tok, scores_node);
  softmax_mix_kernel<<<kB, 512, 0, stream>>>(scores_node, scores_tok, n2t,
                                             mask_tok, mask_nd, out_final,
                                             out_attn_node, out_flow);
  ct_flow1_kernel<<<768, 512, 0, stream>>>(out_final, enc_tok, out_attn_node,
                                           graph, ctp, fp1);
  ct_flow2_kernel<<<320, 512, 0, stream>>>(ctp, fp1, out_attn_node, graph,
                                           out_ct, out_flow);
}

// Round 9
// 234.739 us; speedup vs baseline: 1.0202x; 1.0202x over previous
//
#include <hip/hip_runtime.h>
#include <math.h>

// Problem constants (reference: B=64, TK=512, NK=256, H=512, fp32 in/out)
constexpr int kB = 64;
constexpr int kTK = 512;
constexpr int kNK = 256;
constexpr int kH = 512;
constexpr int kTokBlocks = kB * kTK / 64;   // 512
constexpr int kNodeBlocks = kB * kNK / 64;  // 256

typedef float f32x4 __attribute__((ext_vector_type(4)));
typedef unsigned uint4v __attribute__((ext_vector_type(4)));
typedef __bf16 bf16x8 __attribute__((ext_vector_type(8)));

__device__ __forceinline__ unsigned short f32_to_bf16(float f) {
  return (unsigned short)((__float_as_uint(f) + 0x8000u) >> 16);
}

__device__ __forceinline__ unsigned pk_bf16x2(float lo, float hi) {
  return (unsigned)f32_to_bf16(lo) | ((unsigned)f32_to_bf16(hi) << 16);
}

__device__ __forceinline__ float tanh_fast(float x) {
  float e = __builtin_amdgcn_exp2f(x * 2.8853900817779268f);  // e^{2x}
  return 1.0f - 2.0f * __builtin_amdgcn_rcpf(e + 1.0f);
}

// Drain LDS only, leave global loads in flight across the barrier.
__device__ __forceinline__ void lds_barrier() {
  __builtin_amdgcn_s_waitcnt(0xC07F);
  __builtin_amdgcn_s_barrier();
}

// Async global->LDS, 16B per lane. LDS dest = wave-uniform base + lane*16.
__device__ __forceinline__ void gload_lds16(const void* g, void* l) {
  __builtin_amdgcn_global_load_lds(
      (__attribute__((address_space(1))) void*)(g),
      (__attribute__((address_space(3))) void*)(l), 16, 0, 0);
}

// ---------------------------------------------------------- prep kernel
// blocks [0,512): W transpose->bf16 [n][k]; blocks [512,1024): dec partials.
__global__ __launch_bounds__(256) void prep_kernel(
    const float* __restrict__ Wtok, const float* __restrict__ Wnode,
    unsigned short* __restrict__ WtokT, unsigned short* __restrict__ WnodeT,
    const float* __restrict__ s_t_hat, const float* __restrict__ W_dec,
    float* __restrict__ dec_part) {
  __shared__ float sm[32 * 33];
  const int tid = threadIdx.x;
  if (blockIdx.x < 512) {
    const int idx = blockIdx.x;
    const int z = idx >> 8, rem = idx & 255;
    const int bx = rem & 15, by = rem >> 4;
    const float* W = z ? Wnode : Wtok;
    unsigned short* T = z ? WnodeT : WtokT;
    const int tx = tid & 31, ty = tid >> 5;
#pragma unroll
    for (int i = 0; i < 4; ++i)
      sm[(ty + 8 * i) * 33 + tx] =
          W[(size_t)(by * 32 + ty + 8 * i) * kH + bx * 32 + tx];
    __syncthreads();
#pragma unroll
    for (int i = 0; i < 4; ++i)
      T[(size_t)(bx * 32 + ty + 8 * i) * kH + by * 32 + tx] =
          f32_to_bf16(sm[tx * 33 + ty + 8 * i]);
  } else {
    const int r = blockIdx.x - 512;
    const int b = r >> 3, s = r & 7;
    if (tid < 128) sm[tid] = s_t_hat[(size_t)b * 1024 + s * 128 + tid];
    __syncthreads();
    float a0 = 0.f, a1 = 0.f;
    const float* w = W_dec + (size_t)(s * 128) * kH;
#pragma unroll 8
    for (int k = 0; k < 128; ++k) {
      a0 = fmaf(sm[k], w[(size_t)k * kH + tid], a0);
      a1 = fmaf(sm[k], w[(size_t)k * kH + tid + 256], a1);
    }
    dec_part[(size_t)(b * 8 + s) * kH + tid] = a0;
    dec_part[(size_t)(b * 8 + s) * kH + tid + 256] = a1;
  }
}

// ---------------------------------------------------------- fused scores
// 512 threads = 8 waves. Block tile 64 rows x 512 cols, BK=64, 8 chunks.
// Wave w owns cols [64w,64w+64): 4(m) x 4(n) mfma 16x16x32_bf16.
// ROUND-8 pipeline fixes (vs round 6), per the in-order-vmcnt analysis:
//  (1) 2-deep DMA: fbuf[3], stage(kc+2) each chunk; chunk-top wait is
//      COUNTED vmcnt(2) (drain stage(kc), keep stage(kc+1) in flight).
//  (2) B-burst-then-stage: all 8 B frags of the chunk load in one burst
//      BEFORE the DMA issue. vmcnt retires in issue order, so B consumption
//      no longer drains a just-issued HBM DMA (the round 5-7 self-defeat:
//      mid-chunk loadBs issued after stage() serialized one HBM round-trip
//      per chunk per barrier-locked block).
//  (3) Wave-private cvt: wave w converts exactly the rows it staged, so its
//      own vmcnt guards its reads (round 6/7 raced on other waves' DMA).
// LDS 66 KB (fbuf 48 + hbuf 16 + red 2). Regs ~155 combined -> (512,3),
// no spill, 1 block/CU: the bet is pipeline depth, not residency.
// NOTE round-8 lesson: __builtin_amdgcn_s_waitcnt arg must be a LITERAL
// constant -- a ternary on the (unrolled) loop index fails sema. Use
// if/else with literal args.
__global__ __launch_bounds__(512, 3) void scores_fused_kernel(
    const float* __restrict__ enc_tok, const float* __restrict__ enc_node,
    const unsigned short* __restrict__ WtokT,
    const unsigned short* __restrict__ WnodeT,
    const float* __restrict__ dec_part, const float* __restrict__ b_dec,
    const float* __restrict__ flow, const float* __restrict__ W_c,
    const float* __restrict__ v_tok, const float* __restrict__ v_node,
    float* __restrict__ scores_tok, float* __restrict__ scores_node) {
  const int tid = threadIdx.x;
  const int wave = tid >> 6, lane = tid & 63;
  const int quad = lane >> 4, l15 = lane & 15;
  const bool is_node = blockIdx.x >= kTokBlocks;
  const int bidx = is_node ? (int)blockIdx.x - kTokBlocks : (int)blockIdx.x;
  const float* A = is_node ? enc_node : enc_tok;
  const unsigned short* WT = is_node ? WnodeT : WtokT;
  const float* v = is_node ? v_node : v_tok;
  float* scores = is_node ? scores_node : scores_tok;
  const int ROWS = is_node ? kNK : kTK;
  const int b = is_node ? (bidx >> 2) : (bidx >> 3);
  const int row0 = (is_node ? (bidx & 3) : (bidx & 7)) * 64;

  __shared__ __align__(16) float fbuf[3][4096];           // 16 KB x3, f32 [64][64] linear
  __shared__ __align__(16) unsigned short hbuf[2][4096];  // 8 KB x2, bf16 [64][64] swizzled
  __shared__ float red[8][64];

  const f32x4 fzero = {0.f, 0.f, 0.f, 0.f};
  f32x4 acc[4][4];
#pragma unroll
  for (int i = 0; i < 4; ++i)
#pragma unroll
    for (int j = 0; j < 4; ++j) acc[i][j] = fzero;

  // --- A staging (raw f32, linear, wave-private rows [8w, 8w+8)) ----
  const float* asrcw =
      A + (size_t)(b * ROWS + row0 + wave * 8 + (lane >> 4)) * kH + (lane & 15) * 4;
  auto stage = [&](int kc, int buf) {
    gload_lds16(asrcw + kc * 64, &fbuf[buf][(wave * 8) * 64]);
    gload_lds16(asrcw + (size_t)4 * kH + kc * 64, &fbuf[buf][(wave * 8 + 4) * 64]);
  };

  // --- wave-private cvt: rows [8w, 8w+8) of fbuf[fb] -> hbuf[hb] -----
  // lane l: row = 8w + (l>>3), k0 = (l&7)*8; one b128 read pair + b128 write.
  // hbuf byte addr (row,k): row*128 + ((k>>3)^(row&7))*16 + (k&7)*2.
  const int crow = wave * 8 + (lane >> 3);
  const int ck0 = (lane & 7) * 8;
  const int cdst = crow * 128 + (((ck0 >> 3) ^ (crow & 7)) * 16);
  auto cvt = [&](int fb, int hb) {
    const f32x4 x0 = *(const f32x4*)&fbuf[fb][crow * 64 + ck0];
    const f32x4 x1 = *(const f32x4*)&fbuf[fb][crow * 64 + ck0 + 4];
    uint4v h;
    h[0] = pk_bf16x2(x0[0], x0[1]);
    h[1] = pk_bf16x2(x0[2], x0[3]);
    h[2] = pk_bf16x2(x1[0], x1[1]);
    h[3] = pk_bf16x2(x1[2], x1[3]);
    *(uint4v*)((char*)&hbuf[hb][0] + cdst) = h;
  };

  // --- frag read: pure bf16 ds_read_b128 ----------------------------
  auto readfrag = [&](int buf, int ks, int mi) {
    const int row = mi * 16 + l15;
    const int s16 = (ks * 4 + quad) ^ (row & 7);
    return *(const bf16x8*)((const char*)&hbuf[buf][0] + row * 128 + s16 * 16);
  };

  // B: wave owns cols [64w, 64w+64). Whole-chunk burst: 8 frags (32 VGPR).
  const int n0 = wave * 64;
  const unsigned short* bbase = WT + (size_t)(n0 + l15) * kH + quad * 8;
  bf16x8 bbuf[8];  // frag f = (ks = f>>2, ni = f&3)
  auto loadBburst = [&](int kc) {
#pragma unroll
    for (int f = 0; f < 8; ++f) {
      const int ks = f >> 2, ni = f & 3;
      bbuf[f] = *(const bf16x8*)(bbase + (size_t)(16 * ni) * kH +
                                 (kc * 2 + ks) * 32);
    }
  };

  stage(0, 0);
  stage(1, 1);

#pragma unroll
  for (int kc = 0; kc < 8; ++kc) {
    // drain stage(kc); keep stage(kc+1) flying (vmcnt counted, in-order)
    if (kc < 7) {
      __builtin_amdgcn_s_waitcnt(0x0F72);   // vmcnt(2)
    } else {
      __builtin_amdgcn_s_waitcnt(0x0F70);   // vmcnt(0)
    }
    __builtin_amdgcn_sched_barrier(0);    // rule #18: pin the wait
    cvt(kc % 3, kc & 1);
    loadBburst(kc);                       // B (L2) issued BEFORE the DMA
    __builtin_amdgcn_sched_barrier(0);    // keep burst older than stage
    if (kc < 6) stage(kc + 2, (kc + 2) % 3);
    lds_barrier();                        // hbuf[kc&1] visible block-wide
#pragma unroll
    for (int ks = 0; ks < 2; ++ks) {
      bf16x8 afr[4];
#pragma unroll
      for (int mi = 0; mi < 4; ++mi) afr[mi] = readfrag(kc & 1, ks, mi);
      __builtin_amdgcn_s_setprio(1);
#pragma unroll
      for (int mi = 0; mi < 4; ++mi)
#pragma unroll
        for (int ni = 0; ni < 4; ++ni)
          acc[mi][ni] = __builtin_amdgcn_mfma_f32_16x16x32_bf16(
              afr[mi], bbuf[ks * 4 + ni], acc[mi][ni], 0, 0, 0);
      __builtin_amdgcn_s_setprio(0);
    }
  }

  // epilogue; C/D: col = n0+16ni+l15, row = 16mi+quad*4+reg
  float dec2[4], vv2[4], wc2[4];
#pragma unroll
  for (int ni = 0; ni < 4; ++ni) {
    const int col = n0 + 16 * ni + l15;
    float d = b_dec[col];
#pragma unroll
    for (int p = 0; p < 8; ++p) d += dec_part[(size_t)(b * 8 + p) * kH + col];
    dec2[ni] = d;
    vv2[ni] = v[col];
    wc2[ni] = is_node ? W_c[col] : 0.f;
  }
#pragma unroll
  for (int mi = 0; mi < 4; ++mi) {
#pragma unroll
    for (int reg = 0; reg < 4; ++reg) {
      const int row = 16 * mi + quad * 4 + reg;
      const float fl = is_node ? flow[b * kNK + row0 + row] : 0.f;
      float p = 0.f;
#pragma unroll
      for (int ni = 0; ni < 4; ++ni)
        p += tanh_fast(fmaf(fl, wc2[ni], acc[mi][ni][reg] + dec2[ni])) * vv2[ni];
#pragma unroll
      for (int off = 1; off < 16; off <<= 1) p += __shfl_xor(p, off, 64);
      if (l15 == 0) red[wave][row] = p;
    }
  }
  __syncthreads();
  if (tid < 64) {
    float s = 0.f;
#pragma unroll
    for (int w = 0; w < 8; ++w) s += red[w][tid];
    scores[b * ROWS + row0 + tid] = s;
  }
}

// ---------------------------------------------------------- softmax/mix (+zero flow)
__device__ __forceinline__ float block_sum_512(float v, float* rbuf) {
#pragma unroll
  for (int off = 32; off >= 1; off >>= 1) v += __shfl_xor(v, off, 64);
  if ((threadIdx.x & 63) == 0) rbuf[threadIdx.x >> 6] = v;
  __syncthreads();
  float s = rbuf[0];
#pragma unroll
  for (int w = 1; w < 8; ++w) s += rbuf[w];
  __syncthreads();
  return s;
}

__global__ __launch_bounds__(512) void softmax_mix_kernel(
    const float* __restrict__ scores_node, const float* __restrict__ scores_tok,
    const int* __restrict__ node_to_token,
    const float* __restrict__ mask_tok, const float* __restrict__ mask_node,
    float* __restrict__ out_final, float* __restrict__ out_attn_node,
    float* __restrict__ out_flow) {
  const int b = blockIdx.x, tid = threadIdx.x;
  __shared__ float an_sh[kNK];
  __shared__ float rbuf[8];

  if (tid < kNK) out_flow[b * kNK + tid] = 0.f;  // init for flow2 atomics

  float en = 0.f;
  if (tid < kNK)
    en = expf(scores_node[b * kNK + tid]) * mask_node[b * kNK + tid];
  float sn = block_sum_512(en, rbuf);
  float an = en / sn;
  if (tid < kNK) {
    an_sh[tid] = an;
    out_attn_node[b * kNK + tid] = an;
  }
  __syncthreads();

  const float mt = mask_tok[b * kTK + tid];
  const int idx = node_to_token[b * kTK + tid];
  float eg = expf(an_sh[idx]) * mt;
  float sg = block_sum_512(eg, rbuf);
  float an2t = eg / sg;

  float et = expf(scores_tok[b * kTK + tid]) * mt;
  float st = block_sum_512(et, rbuf);
  float at = et / st;

  out_final[b * kTK + tid] = 0.5f * (at + an2t);
}

// ---------------------------------------------------------- ct_partial + flow1
// blocks [0,512): ct partial (b, 64-row slice s of 8) -> ctp[b*8+s][512].
// blocks [512,768): one_hop partials -> fp1[b][4][256].
__global__ __launch_bounds__(512) void ct_flow1_kernel(
    const float* __restrict__ final_attn, const float* __restrict__ enc_tok,
    const float* __restrict__ attn_node, const float* __restrict__ graph,
    float* __restrict__ ctp, float* __restrict__ fp1) {
  const int tid = threadIdx.x;
  if (blockIdx.x < 512) {
    const int b = blockIdx.x >> 3, s = blockIdx.x & 7;
    __shared__ float fa[64];
    __shared__ float part[4][512];
    if (tid < 64) fa[tid] = final_attn[b * kTK + s * 64 + tid];
    __syncthreads();
    const int h4 = (tid & 127) * 4, tsub = tid >> 7;   // 4 tsubs x 16 rows
    float4 acc = {0.f, 0.f, 0.f, 0.f};
    const float* base =
        enc_tok + ((size_t)(b * kTK + s * 64 + tsub * 16)) * kH + h4;
#pragma unroll
    for (int t = 0; t < 16; ++t) {
      float4 e = *(const float4*)(base + (size_t)t * kH);
      const float w = fa[tsub * 16 + t];
      acc.x = fmaf(w, e.x, acc.x); acc.y = fmaf(w, e.y, acc.y);
      acc.z = fmaf(w, e.z, acc.z); acc.w = fmaf(w, e.w, acc.w);
    }
    *(float4*)&part[tsub][h4] = acc;
    __syncthreads();
    if (tid < 128) {
      float4 s0 = {0.f, 0.f, 0.f, 0.f};
#pragma unroll
      for (int p = 0; p < 4; ++p) {
        float4 pp = *(const float4*)&part[p][tid * 4];
        s0.x += pp.x; s0.y += pp.y; s0.z += pp.z; s0.w += pp.w;
      }
      *(float4*)&ctp[((size_t)(b * 8 + s)) * kH + tid * 4] = s0;
    }
  } else {
    const int rr = blockIdx.x - 512;
    const int b = rr >> 2, sl = rr & 3;
    __shared__ float z[64];
    __shared__ float part[8][256];
    if (tid < 64) z[tid] = attn_node[b * kNK + sl * 64 + tid];
    __syncthreads();
    const int m4 = (tid & 63) * 4, nsub = tid >> 6;
    float4 acc = {0.f, 0.f, 0.f, 0.f};
    const float* g =
        graph + ((size_t)(b * kNK + sl * 64 + nsub * 8)) * kNK + m4;
#pragma unroll
    for (int n = 0; n < 8; ++n) {
      float4 gg = *(const float4*)(g + (size_t)n * kNK);
      const float w = z[nsub * 8 + n];
      acc.x = fmaf(w, gg.x, acc.x); acc.y = fmaf(w, gg.y, acc.y);
      acc.z = fmaf(w, gg.z, acc.z); acc.w = fmaf(w, gg.w, acc.w);
    }
    *(float4*)&part[nsub][m4] = acc;
    __syncthreads();
    if (tid < 64) {
      float4 s0 = {0.f, 0.f, 0.f, 0.f};
#pragma unroll
      for (int p = 0; p < 8; ++p) {
        float4 pp = *(const float4*)&part[p][tid * 4];
        s0.x += pp.x; s0.y += pp.y; s0.z += pp.z; s0.w += pp.w;
      }
      *(float4*)&fp1[((size_t)(b * 4 + sl)) * kNK + tid * 4] = s0;
    }
  }
}

// ---------------------------------------------------------- ct_reduce + flow 2-hop
__global__ __launch_bounds__(512) void ct_flow2_kernel(
    const float* __restrict__ ctp, const float* __restrict__ fp1,
    const float* __restrict__ attn_node, const float* __restrict__ graph,
    float* __restrict__ out_ct, float* __restrict__ out_flow) {
  const int tid = threadIdx.x;
  if (blockIdx.x < 64) {
    const int b = blockIdx.x;
    __shared__ float acc_sh[4][512];
    const int h4 = (tid & 127) * 4, part = tid >> 7;
    float4 a = {0.f, 0.f, 0.f, 0.f};
#pragma unroll
    for (int j = 0; j < 2; ++j) {
      float4 c = *(const float4*)&ctp[((size_t)(b * 8 + part * 2 + j)) * kH + h4];
      a.x += c.x; a.y += c.y; a.z += c.z; a.w += c.w;
    }
    *(float4*)&acc_sh[part][h4] = a;
    __syncthreads();
    if (tid < 128) {
      float4 s = {0.f, 0.f, 0.f, 0.f};
#pragma unroll
      for (int p = 0; p < 4; ++p) {
        float4 pp = *(const float4*)&acc_sh[p][tid * 4];
        s.x += pp.x; s.y += pp.y; s.z += pp.z; s.w += pp.w;
      }
      *(float4*)&out_ct[b * kH + tid * 4] = s;
    }
  } else {
    const int rr = blockIdx.x - 64;
    const int b = rr >> 2, sl = rr & 3;
    __shared__ float one_sh[64];
    __shared__ float part2[8][256];
    if (tid < 64) {
      const int n = sl * 64 + tid;
      float one = 0.f;
#pragma unroll
      for (int p = 0; p < 4; ++p) one += fp1[((size_t)(b * 4 + p)) * kNK + n];
      one_sh[tid] = one;
      atomicAdd(&out_flow[b * kNK + n],
                (attn_node[b * kNK + n] + one) * 0.33333f);
    }
    __syncthreads();
    const int m4 = (tid & 63) * 4, nsub = tid >> 6;
    float4 acc = {0.f, 0.f, 0.f, 0.f};
    const float* g =
        graph + ((size_t)(b * kNK + sl * 64 + nsub * 8)) * kNK + m4;
#pragma unroll
    for (int n = 0; n < 8; ++n) {
      float4 gg = *(const float4*)(g + (size_t)n * kNK);
      const float w = one_sh[sl * 0 + nsub * 8 + n];
      acc.x = fmaf(w, gg.x, acc.x); acc.y = fmaf(w, gg.y, acc.y);
      acc.z = fmaf(w, gg.z, acc.z); acc.w = fmaf(w, gg.w, acc.w);
    }
    *(float4*)&part2[nsub][m4] = acc;
    __syncthreads();
    if (tid < 64) {
      float4 s = {0.f, 0.f, 0.f, 0.f};
#pragma unroll
      for (int p = 0; p < 8; ++p) {
        float4 pp = *(const float4*)&part2[p][tid * 4];
        s.x += pp.x; s.y += pp.y; s.z += pp.z; s.w += pp.w;
      }
      float* dst = &out_flow[b * kNK + tid * 4];
      atomicAdd(dst + 0, s.x * 0.33333f);
      atomicAdd(dst + 1, s.y * 0.33333f);
      atomicAdd(dst + 2, s.z * 0.33333f);
      atomicAdd(dst + 3, s.w * 0.33333f);
    }
  }
}

// ---------------------------------------------------------------- launch
extern "C" void kernel_launch(void* const* d_in, const int* in_sizes, int n_in,
                              void* d_out, int out_size, void* d_ws, size_t ws_size,
                              hipStream_t stream) {
  (void)in_sizes; (void)n_in; (void)out_size; (void)ws_size;
  const float* s_t_hat  = (const float*)d_in[0];
  const float* enc_tok  = (const float*)d_in[1];
  const float* enc_node = (const float*)d_in[2];
  const int*   n2t      = (const int*)d_in[3];
  const float* mask_tok = (const float*)d_in[4];
  const float* mask_nd  = (const float*)d_in[5];
  const float* graph    = (const float*)d_in[6];
  const float* flow     = (const float*)d_in[7];
  const float* W_c      = (const float*)d_in[8];
  const float* W_tok    = (const float*)d_in[9];
  const float* W_node   = (const float*)d_in[10];
  const float* W_dec    = (const float*)d_in[11];
  const float* b_dec    = (const float*)d_in[12];
  const float* v_tok    = (const float*)d_in[13];
  const float* v_node   = (const float*)d_in[14];

  float* out = (float*)d_out;   // c_t | final_attn | attn_dist_node | flow_out
  float* out_ct        = out;
  float* out_final     = out + kB * kH;
  float* out_attn_node = out + 2 * kB * kH;
  float* out_flow      = out_attn_node + kB * kNK;

  // workspace (float offsets):
  float* ws = (float*)d_ws;
  float* scores_tok  = ws;                    // 32768
  float* scores_node = ws + 32768;            // 16384
  float* dec_part    = ws + 49152;            // 262144 (consumed by scores)
  float* ctp         = dec_part;              // alias: 64*8*512 = 262144
  float* fp1         = ws + 311296;           // 64*4*256 = 65536
  unsigned short* WtokT  = (unsigned short*)(ws + 376832);
  unsigned short* WnodeT = WtokT + kH * kH;

  prep_kernel<<<1024, 256, 0, stream>>>(W_tok, W_node, WtokT, WnodeT,
                                        s_t_hat, W_dec, dec_part);
  scores_fused_kernel<<<kTokBlocks + kNodeBlocks, 512, 0, stream>>>(
      enc_tok, enc_node, WtokT, WnodeT, dec_part, b_dec, flow, W_c,
      v_tok, v_node, scores_tok, scores_node);
  softmax_mix_kernel<<<kB, 512, 0, stream>>>(scores_node, scores_tok, n2t,
                                             mask_tok, mask_nd, out_final,
                                             out_attn_node, out_flow);
  ct_flow1_kernel<<<768, 512, 0, stream>>>(out_final, enc_tok, out_attn_node,
                                           graph, ctp, fp1);
  ct_flow2_kernel<<<320, 512, 0, stream>>>(ctp, fp1, out_attn_node, graph,
                                           out_ct, out_flow);
}